// Round 5
// baseline (24561.391 us; speedup 1.0000x reference)
//
#include <hip/hip_runtime.h>
#include <stdint.h>

#define RTOT    16384      // B*N
#define ADIM    20
#define STOCHD  1024
#define DETERD  2048
#define HID     1024
#define GATE3   6144
#define NCAT    32
#define NCLS    32

// ============================ GEMM =====================================
// C[M,N] = act( A[M,K] @ B + bias (+ Cold) )
// BT=false: B is [K,N] row-major. BT=true: B is [N,K] row-major (x @ W^T).
// Block tile 256x128, BK=16, 256 threads, 16x8 per thread, float4 I/O.
// All K used here are multiples of 16. M multiples of 256, N of 128.
// Numerics: each output element is ONE sequential fmaf chain over k
// (+ one final add for ACC) — stays ~1e-6 of the fp32 reference.
template<bool BT, bool BIAS, bool RELU, bool ACC>
__global__ __launch_bounds__(256)
void gemm256(const float* __restrict__ A, const float* __restrict__ B,
             const float* __restrict__ bias, float* __restrict__ C,
             int M, int N, int K, int lda, int ldb, int ldc)
{
  // As padded 256->260: staging scatter (4 lanes share m, kq in {0,4,8,12})
  // lands 2-way per bank (free, m136). Row = 1040 B, 16B-aligned.
  __shared__ __align__(16) float As[16][260];   // [k][m]
  // Bs padded 128->132 (528 B rows, 16B-aligned): BT store scatter 2-way.
  __shared__ __align__(16) float Bs[16][132];   // [k][n]
  const int tid = threadIdx.x;
  const int m0 = blockIdx.y * 256;
  const int n0 = blockIdx.x * 128;
  const int tm = tid >> 4;      // 0..15
  const int tn = tid & 15;      // 0..15

  float acc[16][8];
#pragma unroll
  for (int i = 0; i < 16; ++i)
#pragma unroll
    for (int j = 0; j < 8; ++j) acc[i][j] = 0.0f;

  const int nk = K >> 4;
  for (int kt = 0; kt < nk; ++kt) {
    const int k0 = kt << 4;

    // ---- stage A: 256 rows x 16 k = 1024 float4, 4 per thread ----
    {
      const int mA = tid >> 2;
      const int kq = (tid & 3) << 2;
#pragma unroll
      for (int L = 0; L < 4; ++L) {
        float4 v = *(const float4*)(A + (size_t)(m0 + mA + 64 * L) * lda + (k0 + kq));
        const int m = mA + 64 * L;
        As[kq + 0][m] = v.x; As[kq + 1][m] = v.y;
        As[kq + 2][m] = v.z; As[kq + 3][m] = v.w;
      }
    }

    if constexpr (BT) {
      // B[N,K]: 128 rows x 16 k. 4 consecutive lanes read one 64B row seg.
      const int nB = tid >> 2;
      const int kq = (tid & 3) << 2;
#pragma unroll
      for (int L = 0; L < 2; ++L) {
        const int n = nB + 64 * L;
        float4 v = *(const float4*)(B + (size_t)(n0 + n) * ldb + (k0 + kq));
        Bs[kq + 0][n] = v.x; Bs[kq + 1][n] = v.y;
        Bs[kq + 2][n] = v.z; Bs[kq + 3][n] = v.w;
      }
    } else {
      // B[K,N]: 16 k x 128 n; k = tid>>5 (+8), n = (tid&31)*4.
      const int kB = tid >> 5;
      const int nq = (tid & 31) << 2;
#pragma unroll
      for (int L = 0; L < 2; ++L) {
        const int kk = kB + 8 * L;
        float4 v = *(const float4*)(B + (size_t)(k0 + kk) * ldb + n0 + nq);
        *(float4*)&Bs[kk][nq] = v;
      }
    }
    __syncthreads();

#pragma unroll 4
    for (int k = 0; k < 16; ++k) {
      const float4 a0 = *(const float4*)&As[k][tm * 4];
      const float4 a1 = *(const float4*)&As[k][tm * 4 + 64];
      const float4 a2 = *(const float4*)&As[k][tm * 4 + 128];
      const float4 a3 = *(const float4*)&As[k][tm * 4 + 192];
      const float4 b0 = *(const float4*)&Bs[k][tn * 4];
      const float4 b1 = *(const float4*)&Bs[k][tn * 4 + 64];
      const float av[16] = {a0.x, a0.y, a0.z, a0.w, a1.x, a1.y, a1.z, a1.w,
                            a2.x, a2.y, a2.z, a2.w, a3.x, a3.y, a3.z, a3.w};
      const float bv[8]  = {b0.x, b0.y, b0.z, b0.w, b1.x, b1.y, b1.z, b1.w};
#pragma unroll
      for (int i = 0; i < 16; ++i)
#pragma unroll
        for (int j = 0; j < 8; ++j)
          acc[i][j] = fmaf(av[i], bv[j], acc[i][j]);
    }
    __syncthreads();
  }

#pragma unroll
  for (int i = 0; i < 16; ++i) {
    const int m = m0 + tm * 4 + (i & 3) + 64 * (i >> 2);
#pragma unroll
    for (int jh = 0; jh < 2; ++jh) {
      const int n = n0 + tn * 4 + 64 * jh;
      float4 c;
      c.x = acc[i][jh * 4 + 0]; c.y = acc[i][jh * 4 + 1];
      c.z = acc[i][jh * 4 + 2]; c.w = acc[i][jh * 4 + 3];
      float* cp = C + (size_t)m * ldc + n;
      if constexpr (ACC) {
        float4 o = *(const float4*)cp;
        c.x += o.x; c.y += o.y; c.z += o.z; c.w += o.w;
      }
      if constexpr (BIAS) {
        float4 bb = *(const float4*)(bias + n);
        c.x += bb.x; c.y += bb.y; c.z += bb.z; c.w += bb.w;
      }
      if constexpr (RELU) {
        c.x = fmaxf(c.x, 0.f); c.y = fmaxf(c.y, 0.f);
        c.z = fmaxf(c.z, 0.f); c.w = fmaxf(c.w, 0.f);
      }
      *(float4*)cp = c;
    }
  }
}

// ===================== one-hot row-gather kernels ======================
// onehot(actions) @ W1 is a row-gather of W1. These write the PRE-activation
// partial (bias + gathered rows); the stoch GEMM then ACCumulates + ReLUs.
__global__ void gather_g_kernel(const int* __restrict__ pa, const int* __restrict__ poa,
                                const float* __restrict__ W1, const float* __restrict__ b1,
                                float* __restrict__ out)
{
  const int row = blockIdx.x;
  const int c4  = threadIdx.x << 2;            // 256 threads * 4 = 1024 cols
  float4 acc = *(const float4*)(b1 + c4);
  int r0 = pa[row];
  {
    float4 v = *(const float4*)(W1 + (size_t)r0 * HID + c4);
    acc.x += v.x; acc.y += v.y; acc.z += v.z; acc.w += v.w;
  }
#pragma unroll
  for (int s = 0; s < 7; ++s) {
    int r = ADIM + s * ADIM + poa[row * 7 + s];
    float4 v = *(const float4*)(W1 + (size_t)r * HID + c4);
    acc.x += v.x; acc.y += v.y; acc.z += v.z; acc.w += v.w;
  }
  *(float4*)(out + (size_t)row * HID + c4) = acc;
}

__global__ void gather_a_kernel(const int* __restrict__ pa,
                                const float* __restrict__ W1, const float* __restrict__ b1,
                                float* __restrict__ out)
{
  const int row = blockIdx.x;
  const int c4  = threadIdx.x << 2;
  float4 acc = *(const float4*)(b1 + c4);
  float4 v = *(const float4*)(W1 + (size_t)pa[row] * HID + c4);
  acc.x += v.x; acc.y += v.y; acc.z += v.z; acc.w += v.w;
  *(float4*)(out + (size_t)row * HID + c4) = acc;
}

// =========================== GRU combine ===============================
__global__ void gru_combine_kernel(const float* __restrict__ gi, const float* __restrict__ gh,
                                   const float* __restrict__ h, float* __restrict__ out, int R)
{
  long q = (long)blockIdx.x * blockDim.x + threadIdx.x;   // float4 index
  if (q >= (long)R * (DETERD / 4)) return;
  int i = (int)(q / (DETERD / 4));
  int j4 = (int)(q - (long)i * (DETERD / 4)) << 2;
  size_t b = (size_t)i * GATE3 + j4;
  float4 gir = *(const float4*)(gi + b);
  float4 giz = *(const float4*)(gi + b + 2048);
  float4 gin = *(const float4*)(gi + b + 4096);
  float4 ghr = *(const float4*)(gh + b);
  float4 ghz = *(const float4*)(gh + b + 2048);
  float4 ghn = *(const float4*)(gh + b + 4096);
  float4 hv  = *(const float4*)(h + (size_t)i * DETERD + j4);
  float4 o;
#define GRU1(X) {                                              \
    float r = 1.0f / (1.0f + expf(-(gir.X + ghr.X)));          \
    float z = 1.0f / (1.0f + expf(-(giz.X + ghz.X)));          \
    float n = tanhf(gin.X + r * ghn.X);                        \
    o.X = (1.0f - z) * n + z * hv.X; }
  GRU1(x) GRU1(y) GRU1(z) GRU1(w)
#undef GRU1
  *(float4*)(out + (size_t)i * DETERD + j4) = o;
}

// ======================= categorical sampler ===========================
__device__ __forceinline__ void threefry2x32(uint32_t k0, uint32_t k1,
                                             uint32_t x0, uint32_t x1,
                                             uint32_t& y0, uint32_t& y1)
{
  uint32_t ks2 = k0 ^ k1 ^ 0x1BD11BDAu;
  uint32_t x = x0 + k0;
  uint32_t y = x1 + k1;
#define TFR(r) { x += y; y = (y << r) | (y >> (32 - r)); y ^= x; }
  TFR(13) TFR(15) TFR(26) TFR(6)   x += k1;  y += ks2 + 1u;
  TFR(17) TFR(29) TFR(16) TFR(24)  x += ks2; y += k0 + 2u;
  TFR(13) TFR(15) TFR(26) TFR(6)   x += k0;  y += k1 + 3u;
  TFR(17) TFR(29) TFR(16) TFR(24)  x += k1;  y += ks2 + 4u;
  TFR(13) TFR(15) TFR(26) TFR(6)   x += ks2; y += k0 + 5u;
#undef TFR
  y0 = x; y1 = y;
}

// One thread per (row, category). Reproduces jax.random.categorical under
// jax_threefry_partitionable=True (default since JAX 0.4.36):
//   per element i of the (B,N,32,32) gumbel tensor (row-major linear index):
//     (y0,y1) = threefry2x32(key=(0,seed), x0=hi32(i)=0, x1=lo32(i)=i)
//     bits    = y0 ^ y1                       // 32-bit XOR fold
//   f = bitcast((bits>>9)|0x3f800000)-1; u = max(tiny, f*(1-tiny)+tiny);
//   g = -log(-log(u)); argmax(g + logits), first occurrence.
__global__ void sampler_kernel(const float* __restrict__ logits, float* __restrict__ stoch,
                               uint32_t key0, uint32_t key1)
{
  int tid = blockIdx.x * blockDim.x + threadIdx.x;
  if (tid >= RTOT * NCAT) return;
  float lg[32];
  const float4* lp = (const float4*)(logits + (size_t)tid * 32);
#pragma unroll
  for (int q = 0; q < 8; ++q) {
    float4 v = lp[q];
    lg[4 * q + 0] = v.x; lg[4 * q + 1] = v.y;
    lg[4 * q + 2] = v.z; lg[4 * q + 3] = v.w;
  }
  uint32_t base = (uint32_t)tid * 32u;
  float best = -INFINITY;
  int bi = 0;
  float lmax = -INFINITY;
#pragma unroll
  for (int k = 0; k < 32; ++k) {
    uint32_t i = base + (uint32_t)k;       // element index < 2^24, hi32 = 0
    uint32_t y0, y1;
    threefry2x32(key0, key1, 0u, i, y0, y1);
    uint32_t bits = y0 ^ y1;               // partitionable 32-bit fold
    float f = __uint_as_float((bits >> 9) | 0x3f800000u) - 1.0f;   // [0,1)
    const float TINY = 1.17549435e-38f;
    float u = fmaxf(TINY, f * (1.0f - TINY) + TINY);
    float g = -logf(-logf(u));
    float v = g + lg[k];
    if (v > best) { best = v; bi = k; }    // strict >: first-max like XLA
    lmax = fmaxf(lmax, lg[k]);
  }
  float e[32];
  float s = 0.0f;
#pragma unroll
  for (int k = 0; k < 32; ++k) { e[k] = expf(lg[k] - lmax); s += e[k]; }
  float* op = stoch + (size_t)tid * 32;
#pragma unroll
  for (int k = 0; k < 32; ++k) {
    float p = e[k] / s;
    float oh = (k == bi) ? 1.0f : 0.0f;
    op[k] = (oh + p) - p;                  // == one_hot + probs - sg(probs)
  }
}

// ============================ host side ================================
static void launch_gemm(hipStream_t st, const float* A, const float* B, const float* bias,
                        float* C, int M, int N, int K, int lda, int ldb, int ldc,
                        bool bt, bool relu, bool acc)
{
  dim3 g(N / 128, M / 256), b(256);
  if (bt)        // x @ W^T + bias (GRU gates)
    gemm256<true,  true,  false, false><<<g, b, 0, st>>>(A, B, bias, C, M, N, K, lda, ldb, ldc);
  else if (acc)  // C = relu(C_old + A@B)   (bias pre-folded into C_old)
    gemm256<false, false, true,  true ><<<g, b, 0, st>>>(A, B, bias, C, M, N, K, lda, ldb, ldc);
  else if (relu) // C = relu(A@B + bias)
    gemm256<false, true,  true,  false><<<g, b, 0, st>>>(A, B, bias, C, M, N, K, lda, ldb, ldc);
  else           // C = A@B + bias
    gemm256<false, true,  false, false><<<g, b, 0, st>>>(A, B, bias, C, M, N, K, lda, ldb, ldc);
}

extern "C" void kernel_launch(void* const* d_in, const int* in_sizes, int n_in,
                              void* d_out, int out_size, void* d_ws, size_t ws_size,
                              hipStream_t stream)
{
  const int*   pa   = (const int*)d_in[0];
  const int*   poa  = (const int*)d_in[1];
  const float* gsto = (const float*)d_in[2];
  const float* gdet = (const float*)d_in[3];
  const float* asto = (const float*)d_in[4];
  const float* adet = (const float*)d_in[5];
  const float* gW1 = (const float*)d_in[6],  *gb1 = (const float*)d_in[7];
  const float* gW2 = (const float*)d_in[8],  *gb2 = (const float*)d_in[9];
  const float* gWi = (const float*)d_in[10], *gWh = (const float*)d_in[11];
  const float* gbi = (const float*)d_in[12], *gbh = (const float*)d_in[13];
  const float* gpW1= (const float*)d_in[14], *gpb1= (const float*)d_in[15];
  const float* gpW2= (const float*)d_in[16], *gpb2= (const float*)d_in[17];
  const float* aW1 = (const float*)d_in[18], *ab1 = (const float*)d_in[19];
  const float* aW2 = (const float*)d_in[20], *ab2 = (const float*)d_in[21];
  const float* aWi = (const float*)d_in[22], *aWh = (const float*)d_in[23];
  const float* abi = (const float*)d_in[24], *abh = (const float*)d_in[25];
  const float* apW1= (const float*)d_in[26], *apb1= (const float*)d_in[27];
  const float* apW2= (const float*)d_in[28], *apb2= (const float*)d_in[29];

  float* out = (float*)d_out;             // outputs, flat in return order
  float* og_logits = out;                 // [16384,1024]
  float* og_stoch  = out + 16777216;      // [16384,1024]
  float* og_det    = out + 33554432;      // [16384,2048]
  float* oa_logits = out + 67108864;      // [16384,1024]
  float* oa_stoch  = out + 83886080;      // [16384,1024]
  float* oa_det    = out + 100663296;     // [16384,2048]

  // ---- adaptive workspace layout (floats) ----
  // R1 = max(16384*1024, CH*6144)  (hidden / gi chunk / prior hidden)
  // R2 = 16384*1024                (MLP output x)
  // R3 = CH*6144                   (gh chunk)
  const size_t flts = ws_size / 4;
  const size_t HBUF = (size_t)RTOT * HID;          // 16.8M floats
  int CH = 256;
  for (int cand = 16384; cand >= 256; cand >>= 1) {
    size_t g3 = (size_t)cand * GATE3;
    size_t r1 = (g3 > HBUF) ? g3 : HBUF;
    if (r1 + HBUF + g3 <= flts) { CH = cand; break; }
  }
  const size_t g3  = (size_t)CH * GATE3;
  const size_t r1c = (g3 > HBUF) ? g3 : HBUF;
  float* R1 = (float*)d_ws;
  float* R2 = R1 + r1c;
  float* R3 = R2 + HBUF;
  const int NCH = RTOT / CH;

  // ---------------- global branch ----------------
  // H1 = relu( gather(one-hot part) + gsto @ gW1[160:] )
  gather_g_kernel<<<RTOT, 256, 0, stream>>>(pa, poa, gW1, gb1, R1);
  launch_gemm(stream, gsto, gW1 + (size_t)8 * ADIM * HID, nullptr, R1,
              RTOT, HID, STOCHD, STOCHD, HID, HID, false, false, true);
  launch_gemm(stream, R1, gW2, gb2, R2, RTOT, HID, HID, HID, HID, HID, false, true, false);
  for (int c = 0; c < NCH; ++c) {
    const float* xc = R2 + (size_t)c * CH * HID;
    const float* hc = gdet + (size_t)c * CH * DETERD;
    launch_gemm(stream, xc, gWi, gbi, R1, CH, GATE3, HID,    HID,    HID,    GATE3, true, false, false);
    launch_gemm(stream, hc, gWh, gbh, R3, CH, GATE3, DETERD, DETERD, DETERD, GATE3, true, false, false);
    long nq = (long)CH * (DETERD / 4);
    gru_combine_kernel<<<(unsigned)((nq + 255) / 256), 256, 0, stream>>>(
        R1, R3, hc, og_det + (size_t)c * CH * DETERD, CH);
  }
  launch_gemm(stream, og_det, gpW1, gpb1, R1, RTOT, HID, DETERD, DETERD, HID, HID, false, true,  false);
  launch_gemm(stream, R1,     gpW2, gpb2, og_logits, RTOT, HID, HID, HID, HID, HID, false, false, false);
  sampler_kernel<<<(RTOT * NCAT) / 256, 256, 0, stream>>>(og_logits, og_stoch, 0u, 42u);

  // ---------------- agent branch ----------------
  gather_a_kernel<<<RTOT, 256, 0, stream>>>(pa, aW1, ab1, R1);
  launch_gemm(stream, asto, aW1 + (size_t)ADIM * HID, nullptr, R1,
              RTOT, HID, STOCHD, STOCHD, HID, HID, false, false, true);
  launch_gemm(stream, R1, aW2, ab2, R2, RTOT, HID, HID, HID, HID, HID, false, true, false);
  for (int c = 0; c < NCH; ++c) {
    const float* xc = R2 + (size_t)c * CH * HID;
    const float* hc = adet + (size_t)c * CH * DETERD;
    launch_gemm(stream, xc, aWi, abi, R1, CH, GATE3, HID,    HID,    HID,    GATE3, true, false, false);
    launch_gemm(stream, hc, aWh, abh, R3, CH, GATE3, DETERD, DETERD, DETERD, GATE3, true, false, false);
    long nq = (long)CH * (DETERD / 4);
    gru_combine_kernel<<<(unsigned)((nq + 255) / 256), 256, 0, stream>>>(
        R1, R3, hc, oa_det + (size_t)c * CH * DETERD, CH);
  }
  // agent prior: relu( [a_det | g_stoch] @ apW1 + apb1 ) as 2 GEMMs
  launch_gemm(stream, oa_det,   apW1,                        apb1,    R1, RTOT, HID, DETERD, DETERD, HID, HID, false, false, false);
  launch_gemm(stream, og_stoch, apW1 + (size_t)DETERD * HID, nullptr, R1, RTOT, HID, STOCHD, STOCHD, HID, HID, false, false, true);
  launch_gemm(stream, R1, apW2, apb2, oa_logits, RTOT, HID, HID, HID, HID, HID, false, false, false);
  sampler_kernel<<<(RTOT * NCAT) / 256, 256, 0, stream>>>(oa_logits, oa_stoch, 0u, 43u);
}